// Round 8
// baseline (148.188 us; speedup 1.0000x reference)
//
#include <hip/hip_runtime.h>
#include <math.h>

#define K 3
#define K2 9
#define BB 4
#define C 64
#define H 128
#define W 128
#define O 64
#define HW (H*W)
#define Ho 128
#define Wo 128
#define TILE 64        // pixels per block (along w)
#define CG 16          // input channels per chunk
#define NCHUNK 4       // C / CG
#define KCH 144        // CG*K2 valid k per chunk (tap-major: k = tap*16 + cl)
#define NSTEP 5        // ceil(KCH/32) K-steps of 32
#define SA_STRIDE 164  // halves per px row (328 B = 82 dwords, 82%32=18 -> <=2-way)

typedef _Float16 half4v __attribute__((ext_vector_type(4)));
typedef _Float16 half8v __attribute__((ext_vector_type(8)));
typedef float float4v __attribute__((ext_vector_type(4)));

__device__ __forceinline__ half8v load_frag_lds(const _Float16* p) {
    half4v a = *(const half4v*)p;        // 8B-aligned (row stride 328B, koff mult of 8)
    half4v b = *(const half4v*)(p + 4);
    return __builtin_shufflevector(a, b, 0, 1, 2, 3, 4, 5, 6, 7);
}
__device__ __forceinline__ void store16_lds(_Float16* d, half8v v) {
    *(half4v*)d       = __builtin_shufflevector(v, v, 0, 1, 2, 3);
    *(half4v*)(d + 4) = __builtin_shufflevector(v, v, 4, 5, 6, 7);
}
__device__ __forceinline__ half8v bcast8(_Float16 w) {
    half8v v = {w, w, w, w, w, w, w, w};
    return v;
}

// ---------------------------------------------------------------------------
// prep_all: blocks [0, BB*H) build xh (NCHW fp32 -> NHWC fp16, LDS transpose);
// blocks [BB*H, BB*H+160) pack MFMA B-fragments (tap-major k = tap*16+cl).
// ---------------------------------------------------------------------------
__global__ __launch_bounds__(256) void prep_all(
    const float* __restrict__ x,
    const float* __restrict__ weight,
    const float* __restrict__ offset_w,
    const float* __restrict__ mod_w,
    _Float16* __restrict__ xh,
    _Float16* __restrict__ wB,
    _Float16* __restrict__ wAB)
{
    int t = threadIdx.x;
    if (blockIdx.x < BB * H) {
        __shared__ _Float16 tile[W][68];     // x-pos x channel (pad 68)
        int by = blockIdx.x;
        int y = by % H, b = by / H;
        int xq = t & 31, cr = t >> 5;        // xq: float4 index, cr: 0..7
        #pragma unroll
        for (int g = 0; g < 8; g++) {
            int c = g * 8 + cr;
            float4v v = *(const float4v*)&x[(((size_t)b * C + c) * H + y) * W + xq * 4];
            tile[xq * 4 + 0][c] = (_Float16)v[0];
            tile[xq * 4 + 1][c] = (_Float16)v[1];
            tile[xq * 4 + 2][c] = (_Float16)v[2];
            tile[xq * 4 + 3][c] = (_Float16)v[3];
        }
        __syncthreads();
        int xp2 = t >> 1, hf = t & 1;        // each thread writes 32 ch = 64 B
        const _Float16* src = &tile[xp2][hf * 32];
        _Float16* dst = xh + (((size_t)b * H + y) * W + xp2) * 64 + hf * 32;
        #pragma unroll
        for (int i = 0; i < 8; i++)
            *(half4v*)(dst + i * 4) = *(const half4v*)(src + i * 4);
    } else {
        int i = (blockIdx.x - BB * H) * 256 + t;
        if (i < NCHUNK * NSTEP * 4 * 64 * 8) {          // 40960
            int jj = i & 7;
            int lane = (i >> 3) & 63;
            int q = (i >> 9) & 3;
            int i2 = i >> 11;
            int cc = i2 / NSTEP, s = i2 % NSTEP;
            int k = s * 32 + ((lane >> 4) & 3) * 8 + jj;
            int o = q * 16 + (lane & 15);
            float wv = 0.f;
            if (k < KCH) {
                int tap = k >> 4, cl = k & 15;
                int c = cc * CG + cl;
                wv = weight[(o * C + c) * 9 + tap];
            }
            wB[i] = (_Float16)wv;
        }
        if (i < NCHUNK * NSTEP * 2 * 64 * 8) {          // 20480
            int jj = i & 7;
            int lane = (i >> 3) & 63;
            int jt = (i >> 9) & 1;
            int i2 = i >> 10;
            int cc = i2 / NSTEP, s = i2 % NSTEP;
            int k = s * 32 + ((lane >> 4) & 3) * 8 + jj;
            int n = jt * 16 + (lane & 15);
            float wv = 0.f;
            if (k < KCH && n < 27) {
                int tap = k >> 4, cl = k & 15;
                int c = cc * CG + cl;
                wv = (n < 18) ? offset_w[(n * C + c) * 9 + tap]
                              : mod_w[((n - 18) * C + c) * 9 + tap];
            }
            wAB[i] = (_Float16)wv;
        }
    }
}

// ---------------------------------------------------------------------------
// fused_kernel: one block per (b,h,64px strip), 256 threads, 4 waves.
// LDS = 28,160 B -> 5 blocks/CU. s_res aliased onto s_A (dead after phase B;
// corrupted k-pad columns re-zeroed). Per-tap gather params hoisted to regs.
// ---------------------------------------------------------------------------
__global__ __launch_bounds__(256) void fused_kernel(
    const _Float16* __restrict__ xh,
    const _Float16* __restrict__ wB,
    const _Float16* __restrict__ wAB,
    const float* __restrict__ bias,
    const float* __restrict__ offset_b,
    const float* __restrict__ mod_b,
    float* __restrict__ out)
{
    __shared__ _Float16 s_A[TILE][SA_STRIDE];   // 20,992 B (A-frags; res/out overlay)
    __shared__ unsigned int s_ai[K2 * TILE];    //  2,304 B (a00 | dx<<14 | dy<<15)
    __shared__ half4v s_wgt[K2 * TILE];         //  4,608 B (fp16 corner products)
    __shared__ float s_mm[TILE];                //    256 B
    float* s_res = (float*)&s_A[0][0];          // overlay [27][65] after phase A
    float* s_out = (float*)&s_A[0][0];          // overlay [64][65] after phase C

    // XCD-aware swizzle: each XCD gets a contiguous 64-row h-band of one image.
    int blk = blockIdx.x;
    int xcd = blk & 7, idx = blk >> 3;
    int b  = xcd >> 1;
    int h  = ((xcd & 1) << 6) | (idx >> 1);
    int wt = idx & 1;
    int t  = threadIdx.x;
    int px = t & 63;
    int q  = t >> 6;                            // wave index (uniform per wave)
    int lane = t & 63;
    int m16 = lane & 15;
    int quad = (lane >> 4) & 3;
    int w0 = wt * TILE;
    int wp = w0 + px;

    // zero k-pad cols 144..160
    for (int z = t; z < TILE * 16; z += 256)
        s_A[z >> 4][KCH + (z & 15)] = (_Float16)0.f;

    const _Float16* xb = xh + (size_t)b * HW * 64;

    // hoisted phase-A tap params (wave q owns taps {2q,2q+1}, wave 0 also 8)
    const _Float16* srcA[3];
    _Float16 mhA[3];
    #pragma unroll
    for (int ti = 0; ti < 3; ti++) {
        int tap = (ti < 2) ? (2 * q + ti) : 8;
        int ki = tap / 3, kj = tap % 3;
        int y = h + ki - 1;
        int xv = wp + kj - 1;
        float m = ((y >= 0 && y < H) ? 1.f : 0.f) * ((xv >= 0 && xv < W) ? 1.f : 0.f);
        int yc = min(max(y, 0), H - 1), xcl = min(max(xv, 0), W - 1);
        srcA[ti] = xb + ((size_t)yc * W + xcl) * 64;
        mhA[ti] = (_Float16)m;
    }

    // ================= phase A: offset/mod conv =================
    float4v acc2[2];
    #pragma unroll
    for (int jt = 0; jt < 2; jt++) { float4v z = {0.f,0.f,0.f,0.f}; acc2[jt] = z; }

    #pragma unroll 1
    for (int cc = 0; cc < NCHUNK; cc++) {
        __syncthreads();
        #pragma unroll
        for (int ti = 0; ti < 3; ti++) {
            if (ti == 2 && q != 0) break;            // wave-uniform
            int tap = (ti < 2) ? (2 * q + ti) : 8;
            const _Float16* src = srcA[ti] + cc * CG;
            half8v v0 = *(const half8v*)src;
            half8v v1 = *(const half8v*)(src + 8);
            half8v vm = bcast8(mhA[ti]);
            v0 *= vm; v1 *= vm;
            _Float16* d = &s_A[px][tap * 16];
            store16_lds(d, v0);
            store16_lds(d + 8, v1);
        }
        __syncthreads();

        int row = q * 16 + m16;
        #pragma unroll
        for (int s = 0; s < NSTEP; s++) {
            int koff = s * 32 + quad * 8;
            half8v af = load_frag_lds(&s_A[row][koff]);
            #pragma unroll
            for (int jt = 0; jt < 2; jt++) {
                int widx = (((cc * NSTEP + s) * 2 + jt) * 64 + lane) * 8;
                half8v bf = *(const half8v*)(wAB + widx);
                acc2[jt] = __builtin_amdgcn_mfma_f32_16x16x32_f16(af, bf, acc2[jt], 0, 0, 0);
            }
        }
    }
    __syncthreads();
    // C layout: col(n)=lane&15, row(px-in-tile)=quad*4+reg; wave q owns px-tile q
    #pragma unroll
    for (int jt = 0; jt < 2; jt++) {
        int n = jt * 16 + m16;
        if (n < 27) {
            #pragma unroll
            for (int r = 0; r < 4; r++)
                s_res[n * 65 + q * 16 + quad * 4 + r] = acc2[jt][r];
        }
    }
    __syncthreads();

    // ================= phase B: bilinear params + modmean =================
    #pragma unroll
    for (int ee = 0; ee < 3; ee++) {
        int e = t + ee * 256;
        if (e < K2 * TILE) {
            int k = e >> 6, p = e & 63;
            float offy = s_res[k * 65 + p] + offset_b[k];
            float offx = s_res[(9 + k) * 65 + p] + offset_b[9 + k];
            float sy = (float)(h + k / 3 - 1) + offy;
            float sx = (float)(w0 + p + k % 3 - 1) + offx;
            float fy = floorf(sy), fx = floorf(sx);
            int y0 = (int)fy, x0 = (int)fx;
            float wy1 = sy - fy, wx1 = sx - fx;
            int y0c = min(max(y0, 0), H - 1), y1c = min(max(y0 + 1, 0), H - 1);
            int x0c = min(max(x0, 0), W - 1), x1c = min(max(x0 + 1, 0), W - 1);
            s_ai[e] = (unsigned int)(y0c * W + x0c)
                    | ((unsigned int)(x1c - x0c) << 14)
                    | ((unsigned int)(y1c - y0c) << 15);
            float wg0 = (1.f - wy1) * ((y0 >= 0 && y0 < H) ? 1.f : 0.f);
            float wg1 = wy1 * ((y0 + 1 >= 0 && y0 + 1 < H) ? 1.f : 0.f);
            float wg2 = (1.f - wx1) * ((x0 >= 0 && x0 < W) ? 1.f : 0.f);
            float wg3 = wx1 * ((x0 + 1 >= 0 && x0 + 1 < W) ? 1.f : 0.f);
            half4v wp4;
            wp4[0] = (_Float16)(wg0 * wg2);   // (y0,x0)
            wp4[1] = (_Float16)(wg0 * wg3);   // (y0,x1)
            wp4[2] = (_Float16)(wg1 * wg2);   // (y1,x0)
            wp4[3] = (_Float16)(wg1 * wg3);   // (y1,x1)
            s_wgt[e] = wp4;
        }
    }
    if (t < TILE) {
        float sm = 0.f;
        #pragma unroll
        for (int m = 0; m < 9; m++) {
            float z = s_res[(18 + m) * 65 + t] + mod_b[m];
            sm += 1.f / (1.f + expf(-z));
        }
        s_mm[t] = sm * (1.f / 9.f);
    }
    __syncthreads();   // s_res reads done; s_ai/s_wgt visible

    // re-zero k-pad cols corrupted by the s_res overlay
    for (int z = t; z < TILE * 16; z += 256)
        s_A[z >> 4][KCH + (z & 15)] = (_Float16)0.f;

    // hoisted phase-C tap params
    const _Float16* baseC[3];
    int dxoC[3], dyoC[3];
    half4v wgC[3];
    #pragma unroll
    for (int ti = 0; ti < 3; ti++) {
        int tap = (ti < 2) ? (2 * q + ti) : 8;
        int e = tap * 64 + px;
        unsigned int ai = s_ai[e];
        wgC[ti] = s_wgt[e];
        int a00 = ai & 0x3FFF;
        dxoC[ti] = ((ai >> 14) & 1) * 64;
        dyoC[ti] = ((ai >> 15) & 1) * (W * 64);
        baseC[ti] = xb + (size_t)a00 * 64;
    }

    // ================= phase C: gather + main MFMA =================
    float4v acc[4];
    #pragma unroll
    for (int i = 0; i < 4; i++) { float4v z = {0.f,0.f,0.f,0.f}; acc[i] = z; }

    #pragma unroll 1
    for (int cc = 0; cc < NCHUNK; cc++) {
        __syncthreads();
        #pragma unroll
        for (int ti = 0; ti < 3; ti++) {
            if (ti == 2 && q != 0) break;            // wave-uniform
            int tap = (ti < 2) ? (2 * q + ti) : 8;
            const _Float16* base = baseC[ti] + cc * CG;
            int dxo = dxoC[ti], dyo = dyoC[ti];
            half4v wg4 = wgC[ti];
            half8v r00a = *(const half8v*)(base);
            half8v r00b = *(const half8v*)(base + 8);
            half8v r01a = *(const half8v*)(base + dxo);
            half8v r01b = *(const half8v*)(base + dxo + 8);
            half8v r10a = *(const half8v*)(base + dyo);
            half8v r10b = *(const half8v*)(base + dyo + 8);
            half8v r11a = *(const half8v*)(base + dyo + dxo);
            half8v r11b = *(const half8v*)(base + dyo + dxo + 8);
            half8v vw00 = bcast8(wg4[0]), vw01 = bcast8(wg4[1]);
            half8v vw10 = bcast8(wg4[2]), vw11 = bcast8(wg4[3]);
            half8v va = r00a * vw00 + r01a * vw01 + r10a * vw10 + r11a * vw11;
            half8v vb = r00b * vw00 + r01b * vw01 + r10b * vw10 + r11b * vw11;
            _Float16* d = &s_A[px][tap * 16];
            store16_lds(d, va);
            store16_lds(d + 8, vb);
        }
        __syncthreads();

        // wave q owns o-tile q; px-tiles i = 0..3
        #pragma unroll
        for (int s = 0; s < NSTEP; s++) {
            int widx = (((cc * NSTEP + s) * 4 + q) * 64 + lane) * 8;
            half8v bf = *(const half8v*)(wB + widx);
            int koff = s * 32 + quad * 8;
            #pragma unroll
            for (int i = 0; i < 4; i++) {
                half8v af = load_frag_lds(&s_A[i * 16 + m16][koff]);
                acc[i] = __builtin_amdgcn_mfma_f32_16x16x32_f16(af, bf, acc[i], 0, 0, 0);
            }
        }
    }

    // ================= epilogue =================
    __syncthreads();
    #pragma unroll
    for (int i = 0; i < 4; i++) {
        int o = q * 16 + m16;
        #pragma unroll
        for (int r = 0; r < 4; r++)
            s_out[o * 65 + i * 16 + quad * 4 + r] = acc[i][r];
    }
    __syncthreads();
    {
        float mm = s_mm[px];
        #pragma unroll
        for (int jj = 0; jj < 16; jj++) {
            int o = q * 16 + jj;
            out[(((size_t)b * O + o) * Ho + h) * Wo + w0 + px] =
                s_out[o * 65 + px] * mm + bias[o];
        }
    }
}

extern "C" void kernel_launch(void* const* d_in, const int* in_sizes, int n_in,
                              void* d_out, int out_size, void* d_ws, size_t ws_size,
                              hipStream_t stream) {
    const float* x        = (const float*)d_in[0];
    const float* weight   = (const float*)d_in[1];
    const float* bias     = (const float*)d_in[2];
    const float* offset_w = (const float*)d_in[3];
    const float* offset_b = (const float*)d_in[4];
    const float* mod_w    = (const float*)d_in[5];
    const float* mod_b    = (const float*)d_in[6];
    float* out = (float*)d_out;

    // Workspace (bytes): wB 81,920 | wAB 40,960 | xh 8,388,608 (16B-aligned)
    _Float16* wB  = (_Float16*)d_ws;            // 40960 halves
    _Float16* wAB = wB + 40960;                 // 20480 halves
    _Float16* xh  = wAB + 20480;                // byte offset 122,880

    prep_all<<<BB * H + 160, 256, 0, stream>>>(
        x, weight, offset_w, mod_w, xh, wB, wAB);

    int nblk = BB * Ho * (Wo / TILE);   // 1024
    fused_kernel<<<nblk, 256, 0, stream>>>(
        xh, wB, wAB, bias, offset_b, mod_b, out);
}

// Round 9
// 109.375 us; speedup vs baseline: 1.3549x; 1.3549x over previous
//
#include <hip/hip_runtime.h>
#include <math.h>

#define K 3
#define K2 9
#define BB 4
#define C 64
#define H 128
#define W 128
#define O 64
#define HW (H*W)
#define Ho 128
#define Wo 128
#define TILE 64        // pixels per block (along w)
#define TSTR 80        // halves per px row in tap tile (160 B, 16B-aligned)

typedef _Float16 half4v __attribute__((ext_vector_type(4)));
typedef _Float16 half8v __attribute__((ext_vector_type(8)));
typedef float float4v __attribute__((ext_vector_type(4)));

__device__ __forceinline__ half8v bcast8(_Float16 w) {
    half8v v = {w, w, w, w, w, w, w, w};
    return v;
}

// ---------------------------------------------------------------------------
// prep_all: blocks [0, BB*H) build xh (NCHW fp32 -> NHWC fp16, LDS transpose);
// blocks [BB*H, BB*H+144) pack MFMA B-fragments, TAP-MAJOR K: k = tap*64 + ch.
//  wB : [tap*2+s][q=o-tile(4)][lane(64)][jj(8)], ch = s*32+(lane>>4)*8+jj
//  wAB: [tap*2+s][jt=n-tile(2)][lane(64)][jj(8)], n = jt*16+(lane&15) in 0..26
// ---------------------------------------------------------------------------
__global__ __launch_bounds__(256) void prep_all(
    const float* __restrict__ x,
    const float* __restrict__ weight,
    const float* __restrict__ offset_w,
    const float* __restrict__ mod_w,
    _Float16* __restrict__ xh,
    _Float16* __restrict__ wB,
    _Float16* __restrict__ wAB)
{
    int t = threadIdx.x;
    if (blockIdx.x < BB * H) {
        __shared__ _Float16 tile[W][68];     // x-pos x channel (pad 68)
        int by = blockIdx.x;
        int y = by % H, b = by / H;
        int xq = t & 31, cr = t >> 5;        // xq: float4 index, cr: 0..7
        #pragma unroll
        for (int g = 0; g < 8; g++) {
            int c = g * 8 + cr;
            float4v v = *(const float4v*)&x[(((size_t)b * C + c) * H + y) * W + xq * 4];
            tile[xq * 4 + 0][c] = (_Float16)v[0];
            tile[xq * 4 + 1][c] = (_Float16)v[1];
            tile[xq * 4 + 2][c] = (_Float16)v[2];
            tile[xq * 4 + 3][c] = (_Float16)v[3];
        }
        __syncthreads();
        int xp2 = t >> 1, hf = t & 1;        // each thread writes 32 ch = 64 B
        const _Float16* src = &tile[xp2][hf * 32];
        _Float16* dst = xh + (((size_t)b * H + y) * W + xp2) * 64 + hf * 32;
        #pragma unroll
        for (int i = 0; i < 8; i++)
            *(half4v*)(dst + i * 4) = *(const half4v*)(src + i * 4);
    } else {
        int i = (blockIdx.x - BB * H) * 256 + t;
        if (i < K2 * 2 * 4 * 64 * 8) {          // 36864
            int jj = i & 7;
            int lane = (i >> 3) & 63;
            int q4 = (i >> 9) & 3;
            int i2 = i >> 11;                    // tap*2 + s, [0,18)
            int tap = i2 >> 1, s = i2 & 1;
            int ch = s * 32 + ((lane >> 4) & 3) * 8 + jj;
            int o = q4 * 16 + (lane & 15);
            wB[i] = (_Float16)weight[(o * C + ch) * 9 + tap];
        }
        if (i < K2 * 2 * 2 * 64 * 8) {          // 18432
            int jj = i & 7;
            int lane = (i >> 3) & 63;
            int jt = (i >> 9) & 1;
            int i2 = i >> 10;                    // tap*2 + s
            int tap = i2 >> 1, s = i2 & 1;
            int ch = s * 32 + ((lane >> 4) & 3) * 8 + jj;
            int n = jt * 16 + (lane & 15);
            float wv = 0.f;
            if (n < 27)
                wv = (n < 18) ? offset_w[(n * C + ch) * 9 + tap]
                              : mod_w[((n - 18) * C + ch) * 9 + tap];
            wAB[i] = (_Float16)wv;
        }
    }
}

// ---------------------------------------------------------------------------
// fused_kernel: one block per (b,h,64px strip), 256 threads, 4 waves.
// Tap-major K (k = tap*64+ch): per tap, a COOPERATIVE gather (64 lanes =
// 8 px x 8 ch-segments -> one instr reads 8 full 128B records = 16 cache
// lines, vs 64 in the lane-per-pixel scheme) fills a double-buffered
// 64px x 64ch fp16 A-tile; 2 MFMA K-steps per tap; 1 barrier per tap with
// next-tap loads issued before the MFMAs (software pipeline).
// ---------------------------------------------------------------------------
__global__ __launch_bounds__(256) void fused_kernel(
    const _Float16* __restrict__ xh,
    const _Float16* __restrict__ wB,
    const _Float16* __restrict__ wAB,
    const float* __restrict__ bias,
    const float* __restrict__ offset_b,
    const float* __restrict__ mod_b,
    float* __restrict__ out)
{
    __shared__ _Float16 s_T[2][TILE][TSTR];     // 20,480 B (A-tiles; overlays)
    __shared__ unsigned int s_ai[K2 * TILE];    //  2,304 B (a00 | dx<<14 | dy<<15)
    __shared__ half4v s_wgt[K2 * TILE];         //  4,608 B (fp16 corner products)
    __shared__ float s_mm[TILE];                //    256 B
    float* s_res = (float*)&s_T[0][0][0];       // overlay [27][65] (phase A out)
    float* s_out = (float*)&s_T[0][0][0];       // overlay [64][65] (epilogue)

    // XCD-aware swizzle: each XCD gets a contiguous 64-row h-band of one image.
    int blk = blockIdx.x;
    int xcd = blk & 7, idx = blk >> 3;
    int b  = xcd >> 1;
    int h  = ((xcd & 1) << 6) | (idx >> 1);
    int wt = idx & 1;
    int t  = threadIdx.x;
    int q  = t >> 6;                            // wave index
    int lane = t & 63;
    int m16 = lane & 15;
    int quad = (lane >> 4) & 3;
    int w0 = wt * TILE;
    int px = lane;                              // epilogue pixel
    int gpx0 = q * 16 + (lane >> 3);            // cooperative gather: px (pg=0)
    int seg  = lane & 7;                        // 16B channel segment

    const _Float16* xb = xh + (size_t)b * HW * 64;

    // ================= phase A: offset/mod conv (tap-pipelined) =============
    float4v acc2[2];
    #pragma unroll
    for (int jt = 0; jt < 2; jt++) { float4v z = {0.f,0.f,0.f,0.f}; acc2[jt] = z; }

    // prologue: gather tap 0 -> buf 0
    #pragma unroll
    for (int pg = 0; pg < 2; pg++) {
        int ppx = gpx0 + pg * 8;
        int y = h - 1;                           // tap0: ki=0, kj=0
        int xv = w0 + ppx - 1;
        float m = ((y >= 0) ? 1.f : 0.f) * ((xv >= 0) ? 1.f : 0.f);
        int yc = max(y, 0), xc = max(xv, 0);
        const _Float16* src = xb + ((size_t)(yc * W + xc)) * 64 + seg * 8;
        half8v v = *(const half8v*)src;
        *(half8v*)&s_T[0][ppx][seg * 8] = v * bcast8((_Float16)m);
    }
    __syncthreads();

    #pragma unroll 1
    for (int tap = 0; tap < K2; tap++) {
        half8v pv[2]; _Float16 pm[2];
        if (tap < 8) {
            int tp = tap + 1;
            int ki = tp / 3, kj = tp % 3;
            int y = h + ki - 1;
            float my = (y >= 0 && y < H) ? 1.f : 0.f;
            int yc = min(max(y, 0), H - 1);
            #pragma unroll
            for (int pg = 0; pg < 2; pg++) {
                int ppx = gpx0 + pg * 8;
                int xv = w0 + ppx + kj - 1;
                pm[pg] = (_Float16)(my * ((xv >= 0 && xv < W) ? 1.f : 0.f));
                int xc = min(max(xv, 0), W - 1);
                pv[pg] = *(const half8v*)(xb + ((size_t)(yc * W + xc)) * 64 + seg * 8);
            }
        }
        int row = q * 16 + m16;
        #pragma unroll
        for (int s = 0; s < 2; s++) {
            half8v af = *(const half8v*)&s_T[tap & 1][row][s * 32 + quad * 8];
            #pragma unroll
            for (int jt = 0; jt < 2; jt++) {
                int widx = (((tap * 2 + s) * 2 + jt) * 64 + lane) * 8;
                half8v bf = *(const half8v*)(wAB + widx);
                acc2[jt] = __builtin_amdgcn_mfma_f32_16x16x32_f16(af, bf, acc2[jt], 0, 0, 0);
            }
        }
        if (tap < 8) {
            #pragma unroll
            for (int pg = 0; pg < 2; pg++)
                *(half8v*)&s_T[(tap + 1) & 1][gpx0 + pg * 8][seg * 8] = pv[pg] * bcast8(pm[pg]);
        }
        __syncthreads();
    }

    // C layout: col(n)=lane&15, row(px-in-tile)=quad*4+reg; wave q owns px-tile q
    #pragma unroll
    for (int jt = 0; jt < 2; jt++) {
        int n = jt * 16 + m16;
        if (n < 27) {
            #pragma unroll
            for (int r = 0; r < 4; r++)
                s_res[n * 65 + q * 16 + quad * 4 + r] = acc2[jt][r];
        }
    }
    __syncthreads();

    // ================= phase B: bilinear params + modmean =================
    #pragma unroll
    for (int ee = 0; ee < 3; ee++) {
        int e = t + ee * 256;
        if (e < K2 * TILE) {
            int k = e >> 6, p = e & 63;
            float offy = s_res[k * 65 + p] + offset_b[k];
            float offx = s_res[(9 + k) * 65 + p] + offset_b[9 + k];
            float sy = (float)(h + k / 3 - 1) + offy;
            float sx = (float)(w0 + p + k % 3 - 1) + offx;
            float fy = floorf(sy), fx = floorf(sx);
            int y0 = (int)fy, x0 = (int)fx;
            float wy1 = sy - fy, wx1 = sx - fx;
            int y0c = min(max(y0, 0), H - 1), y1c = min(max(y0 + 1, 0), H - 1);
            int x0c = min(max(x0, 0), W - 1), x1c = min(max(x0 + 1, 0), W - 1);
            s_ai[e] = (unsigned int)(y0c * W + x0c)
                    | ((unsigned int)(x1c - x0c) << 14)
                    | ((unsigned int)(y1c - y0c) << 15);
            float wg0 = (1.f - wy1) * ((y0 >= 0 && y0 < H) ? 1.f : 0.f);
            float wg1 = wy1 * ((y0 + 1 >= 0 && y0 + 1 < H) ? 1.f : 0.f);
            float wg2 = (1.f - wx1) * ((x0 >= 0 && x0 < W) ? 1.f : 0.f);
            float wg3 = wx1 * ((x0 + 1 >= 0 && x0 + 1 < W) ? 1.f : 0.f);
            half4v wp4;
            wp4[0] = (_Float16)(wg0 * wg2);   // (y0,x0)
            wp4[1] = (_Float16)(wg0 * wg3);   // (y0,x1)
            wp4[2] = (_Float16)(wg1 * wg2);   // (y1,x0)
            wp4[3] = (_Float16)(wg1 * wg3);   // (y1,x1)
            s_wgt[e] = wp4;
        }
    }
    if (t < TILE) {
        float sm = 0.f;
        #pragma unroll
        for (int m = 0; m < 9; m++) {
            float z = s_res[(18 + m) * 65 + t] + mod_b[m];
            sm += 1.f / (1.f + expf(-z));
        }
        s_mm[t] = sm * (1.f / 9.f);
    }
    __syncthreads();

    // ================= phase C: deform gather + main MFMA (tap-pipelined) ===
    float4v acc[4];
    #pragma unroll
    for (int i = 0; i < 4; i++) { float4v z = {0.f,0.f,0.f,0.f}; acc[i] = z; }

    // prologue: gather tap 0 -> buf 0 (overwrites s_res region; phase B done)
    #pragma unroll
    for (int pg = 0; pg < 2; pg++) {
        int ppx = gpx0 + pg * 8;
        unsigned int ai = s_ai[ppx];             // tap 0
        half4v wg = s_wgt[ppx];
        int a00 = ai & 0x3FFF;
        int dxo = ((ai >> 14) & 1) * 64;
        int dyo = ((ai >> 15) & 1) * (W * 64);
        const _Float16* base = xb + (size_t)a00 * 64 + seg * 8;
        half8v r00 = *(const half8v*)(base);
        half8v r01 = *(const half8v*)(base + dxo);
        half8v r10 = *(const half8v*)(base + dyo);
        half8v r11 = *(const half8v*)(base + dyo + dxo);
        half8v v = r00 * bcast8(wg[0]) + r01 * bcast8(wg[1])
                 + r10 * bcast8(wg[2]) + r11 * bcast8(wg[3]);
        *(half8v*)&s_T[0][ppx][seg * 8] = v;
    }
    __syncthreads();

    #pragma unroll 1
    for (int tap = 0; tap < K2; tap++) {
        half8v rr[2][4]; half4v wgp[2];
        if (tap < 8) {
            #pragma unroll
            for (int pg = 0; pg < 2; pg++) {
                int e = (tap + 1) * 64 + gpx0 + pg * 8;
                unsigned int ai = s_ai[e];
                wgp[pg] = s_wgt[e];
                int a00 = ai & 0x3FFF;
                int dxo = ((ai >> 14) & 1) * 64;
                int dyo = ((ai >> 15) & 1) * (W * 64);
                const _Float16* base = xb + (size_t)a00 * 64 + seg * 8;
                rr[pg][0] = *(const half8v*)(base);
                rr[pg][1] = *(const half8v*)(base + dxo);
                rr[pg][2] = *(const half8v*)(base + dyo);
                rr[pg][3] = *(const half8v*)(base + dyo + dxo);
            }
        }
        #pragma unroll
        for (int s = 0; s < 2; s++) {
            int widx = (((tap * 2 + s) * 4 + q) * 64 + lane) * 8;
            half8v bf = *(const half8v*)(wB + widx);
            #pragma unroll
            for (int i = 0; i < 4; i++) {
                half8v af = *(const half8v*)&s_T[tap & 1][i * 16 + m16][s * 32 + quad * 8];
                acc[i] = __builtin_amdgcn_mfma_f32_16x16x32_f16(af, bf, acc[i], 0, 0, 0);
            }
        }
        if (tap < 8) {
            #pragma unroll
            for (int pg = 0; pg < 2; pg++) {
                half4v wg = wgp[pg];
                half8v v = rr[pg][0] * bcast8(wg[0]) + rr[pg][1] * bcast8(wg[1])
                         + rr[pg][2] * bcast8(wg[2]) + rr[pg][3] * bcast8(wg[3]);
                *(half8v*)&s_T[(tap + 1) & 1][gpx0 + pg * 8][seg * 8] = v;
            }
        }
        __syncthreads();
    }

    // ================= epilogue =================
    #pragma unroll
    for (int i = 0; i < 4; i++) {
        int o = q * 16 + m16;
        #pragma unroll
        for (int r = 0; r < 4; r++)
            s_out[o * 65 + i * 16 + quad * 4 + r] = acc[i][r];
    }
    __syncthreads();
    {
        float mm = s_mm[px];
        #pragma unroll
        for (int jj = 0; jj < 16; jj++) {
            int o = q * 16 + jj;
            out[(((size_t)b * O + o) * Ho + h) * Wo + w0 + px] =
                s_out[o * 65 + px] * mm + bias[o];
        }
    }
}

extern "C" void kernel_launch(void* const* d_in, const int* in_sizes, int n_in,
                              void* d_out, int out_size, void* d_ws, size_t ws_size,
                              hipStream_t stream) {
    const float* x        = (const float*)d_in[0];
    const float* weight   = (const float*)d_in[1];
    const float* bias     = (const float*)d_in[2];
    const float* offset_w = (const float*)d_in[3];
    const float* offset_b = (const float*)d_in[4];
    const float* mod_w    = (const float*)d_in[5];
    const float* mod_b    = (const float*)d_in[6];
    float* out = (float*)d_out;

    // Workspace (halves): wB 36,864 | wAB 18,432 | xh 4,194,304 (byte 110,592, 16B-aligned)
    _Float16* wB  = (_Float16*)d_ws;
    _Float16* wAB = wB + 36864;
    _Float16* xh  = wAB + 18432;

    prep_all<<<BB * H + 144, 256, 0, stream>>>(
        x, weight, offset_w, mod_w, xh, wB, wAB);

    int nblk = BB * Ho * (Wo / TILE);   // 1024
    fused_kernel<<<nblk, 256, 0, stream>>>(
        xh, wB, wAB, bias, offset_b, mod_b, out);
}